// Round 7
// baseline (148.695 us; speedup 1.0000x reference)
//
#include <hip/hip_runtime.h>
#include <hip/hip_bf16.h>

// Problem geometry
#define NB   16
#define C0   128
#define HH   44
#define WW   144
#define HW   (HH * WW)        // 6336
#define NPOS (NB * HW)        // 101376
#define SC   8
#define WOUT (WW * SC)        // 1152
#define HOUT (HH * SC)        // 352
#define PI_F 3.1415926535f

typedef __attribute__((ext_vector_type(8))) short bf8;   // 8 bf16 (A/B frag)
typedef __attribute__((ext_vector_type(4))) float f4;    // 4 fp32 (C/D frag)
typedef unsigned short ushort_t;

// d_ws layout (byte offsets):
//   [0, 16384)        conv0 B-frags bf16: 16 chunks (t*4+kk) x [64 lanes][8]
//   [16384, 24576)    wT1 fp32 [c=64][o=32]   (transposed conv1)
//   [24576, 26624)    wT2 fp32 [c=32][o=16]   (transposed conv2)
//   [32768, +12.97MB) h1 bf16 [ch=64][NPOS]   (inter-kernel activation)
#define WS_F0   0
#define WS_WT1  16384
#define WS_WT2  24576
#define WS_H1   32768
#define NPREP   10752   // 8192 + 2048 + 512 work items

__device__ __forceinline__ unsigned f2bf(float f) {
    union { float f; unsigned u; } v; v.f = f;
    unsigned r = v.u + 0x7FFFu + ((v.u >> 16) & 1u);     // RNE
    return r >> 16;
}
__device__ __forceinline__ float bf2f(ushort_t s) {
    union { unsigned u; float f; } v; v.u = ((unsigned)s) << 16; return v.f;
}
__device__ __forceinline__ float eluf(float x) {
    return x > 0.f ? x : (__expf(x) - 1.f);
}
__device__ __forceinline__ float sigmoidf(float x) {
    return 1.f / (1.f + __expf(-x));
}

// ---- prep: conv0 -> frag-exact bf16 chunks; conv1/conv2 -> transposed fp32 ----
__global__ void prep_w(const float* __restrict__ w0, const float* __restrict__ w1,
                       const float* __restrict__ w2, ushort_t* __restrict__ f0,
                       float* __restrict__ wt1, float* __restrict__ wt2) {
    int i = blockIdx.x * 256 + (int)threadIdx.x;
    if (i < 8192) {
        int j = i & 7, lane = (i >> 3) & 63, ch = i >> 9;       // ch = t*4+kk
        int q = lane >> 4, n = lane & 15, kk = ch & 3, t = ch >> 2;
        f0[i] = (ushort_t)f2bf(w0[(t * 16 + n) * 128 + kk * 32 + q * 8 + j]);
    } else if (i < 10240) {
        int i2 = i - 8192;
        int c = i2 >> 5, o = i2 & 31;
        wt1[c * 32 + o] = w1[o * 64 + c];
    } else if (i < NPREP) {
        int i2 = i - 10240;
        int c = i2 >> 4, o = i2 & 15;
        wt2[c * 16 + o] = w2[o * 32 + c];
    }
}

// ---- K1: conv0 (128 -> 64) as bf16 MFMA GEMM + ELU -> h1 bf16 [ch][pos] ----
// One wave = 16 positions, 4 N-tiles x 4 K-steps = 16 MFMA. Short per-wave
// chain (1 load epoch -> MFMA -> store); 6336 waves, 4 resident/SIMD.
__global__ __launch_bounds__(256, 4)
void k1_conv0(const float* __restrict__ x, const ushort_t* __restrict__ fr,
              const float* __restrict__ b0, ushort_t* __restrict__ h1) {
    const int tid  = (int)threadIdx.x;
    const int lane = tid & 63;
    const int wid  = tid >> 6;
    const int q    = lane >> 4;
    const int n    = lane & 15;

    const int p0w = blockIdx.x * 64 + wid * 16;   // wave's position base
    const int pm  = p0w + n;                       // A-row position for loads
    const int bm  = pm / HW;
    const int hwm = pm - bm * HW;

    // A[m=n][k=kk*32+q*8+j]: per instr 4 quads x 16 consecutive pos = 4x64B segs
    const float* xb = x + (size_t)bm * (C0 * HW) + hwm;
    float xr[32];
#pragma unroll
    for (int kk = 0; kk < 4; ++kk)
#pragma unroll
        for (int j = 0; j < 8; ++j)
            xr[kk * 8 + j] = xb[(kk * 32 + q * 8 + j) * HW];

    bf8 A[4];
#pragma unroll
    for (int kk = 0; kk < 4; ++kk) {
        bf8 a;
#pragma unroll
        for (int j = 0; j < 8; j += 2) {
            __hip_bfloat162 pck = __float22bfloat162_rn(
                make_float2(xr[kk * 8 + j], xr[kk * 8 + j + 1]));
            union { __hip_bfloat162 b; short s[2]; } u; u.b = pck;
            a[j] = u.s[0]; a[j + 1] = u.s[1];
        }
        A[kk] = a;
    }

    f4 acc[4];
#pragma unroll
    for (int t = 0; t < 4; ++t) {
        const float bb = b0[t * 16 + n];
        acc[t] = (f4){bb, bb, bb, bb};
    }
#pragma unroll
    for (int t = 0; t < 4; ++t) {
        bf8 B[4];
#pragma unroll
        for (int kk = 0; kk < 4; ++kk)
            B[kk] = *(const bf8*)(fr + (t * 4 + kk) * 512 + lane * 8);
#pragma unroll
        for (int kk = 0; kk < 4; ++kk)
            acc[t] = __builtin_amdgcn_mfma_f32_16x16x32_bf16(A[kk], B[kk], acc[t], 0, 0, 0);
    }

    // C/D: reg r -> pos p0w+4q+r, col n -> ch t*16+n. Pack 4 pos -> one b64 store.
#pragma unroll
    for (int t = 0; t < 4; ++t) {
        unsigned lo = f2bf(eluf(acc[t][0])) | (f2bf(eluf(acc[t][1])) << 16);
        unsigned hi = f2bf(eluf(acc[t][2])) | (f2bf(eluf(acc[t][3])) << 16);
        uint2 v; v.x = lo; v.y = hi;
        *reinterpret_cast<uint2*>(h1 + (size_t)(t * 16 + n) * NPOS + p0w + 4 * q) = v;
    }
}

// ---- K2: conv1..convc + plane math + 8x8 upsample, 1 thread per position ----
// h1 reads channel-major (128 B/wave dense); conv1/conv2 weights transposed
// (wT[c][o], K$-resident ~10 KB -> s_load_dwordx16 batches); all fp32 VALU.
__global__ __launch_bounds__(256, 1)
void k2_rest(const ushort_t* __restrict__ h1,
             const float* __restrict__ wt1, const float* __restrict__ b1,
             const float* __restrict__ wt2, const float* __restrict__ b2,
             const float* __restrict__ w3,  const float* __restrict__ b3,
             const float* __restrict__ w4,  const float* __restrict__ b4,
             const float* __restrict__ wc,  const float* __restrict__ bc,
             float* __restrict__ out) {
    const int p  = blockIdx.x * 256 + (int)threadIdx.x;   // NPOS % 256 == 0
    const int b  = p / HW;
    const int hw = p - b * HW;

    // ---- conv1: 64 -> 32, streaming channel-major ----
    float h2[32];
#pragma unroll
    for (int o = 0; o < 32; ++o) h2[o] = b1[o];
#pragma unroll
    for (int c = 0; c < 64; ++c) {
        const float hv = bf2f(h1[(size_t)c * NPOS + p]);
        const float* wt = wt1 + c * 32;
#pragma unroll
        for (int o = 0; o < 32; ++o) h2[o] = fmaf(hv, wt[o], h2[o]);
    }
#pragma unroll
    for (int o = 0; o < 32; ++o) h2[o] = eluf(h2[o]);

    // ---- conv2: 32 -> 16 ----
    float h3[16];
#pragma unroll
    for (int o = 0; o < 16; ++o) h3[o] = b2[o];
#pragma unroll
    for (int c = 0; c < 32; ++c) {
        const float hv = h2[c];
        const float* wt = wt2 + c * 16;
#pragma unroll
        for (int o = 0; o < 16; ++o) h3[o] = fmaf(hv, wt[o], h3[o]);
    }
#pragma unroll
    for (int o = 0; o < 16; ++o) h3[o] = eluf(h3[o]);

    // ---- conv3: 16 -> 8 ----
    float h4[8];
#pragma unroll
    for (int o = 0; o < 8; ++o) {
        float a = b3[o];
#pragma unroll
        for (int c = 0; c < 16; ++c) a = fmaf(h3[c], w3[o * 16 + c], a);
        h4[o] = eluf(a);
    }

    // ---- conv4: 8 -> 4 (no activation) ----
    float h5[4];
#pragma unroll
    for (int o = 0; o < 4; ++o) {
        float a = b4[o];
#pragma unroll
        for (int c = 0; c < 8; ++c) a = fmaf(h4[c], w4[o * 8 + c], a);
        h5[o] = a;
    }

    // ---- convc: 4 -> 3 ----
    float y0 = bc[0], y1 = bc[1], y2 = bc[2];
#pragma unroll
    for (int c = 0; c < 4; ++c) {
        y0 = fmaf(h5[c], wc[0 * 4 + c], y0);
        y1 = fmaf(h5[c], wc[1 * 4 + c], y1);
        y2 = fmaf(h5[c], wc[2 * 4 + c], y2);
    }

    // ---- plane parameters ----
    const float theta = sigmoidf(y0) * (PI_F / 6.0f);
    const float phi   = sigmoidf(y1) * (PI_F * 2.0f);
    const float dist  = sigmoidf(y2) * 81.0f;
    const float st = __sinf(theta), ct = __cosf(theta);
    const float sp = __sinf(phi),   cp = __cosf(phi);
    float nx = st * cp, ny = st * sp, nz = ct;
    const float inv = rsqrtf(fmaxf(nx * nx + ny * ny + nz * nz, 1e-24f));
    nx *= inv; ny *= inv; nz *= inv;

    // ---- 8x8 upsample + per-pixel depth ----
    const int h = hw / WW;
    const int w = hw - h * WW;
    float* op = out + ((size_t)b * HOUT + (size_t)h * SC) * WOUT + (size_t)w * SC;

    float nxu[8];
#pragma unroll
    for (int j = 0; j < 8; ++j) nxu[j] = nx * ((j - 3.5f) * 0.125f);

#pragma unroll
    for (int i = 0; i < 8; ++i) {
        const float den0 = fmaf(ny, (i - 3.5f) * 0.125f, nz);
        float d[8];
#pragma unroll
        for (int j = 0; j < 8; ++j)
            d[j] = dist * __builtin_amdgcn_rcpf(den0 + nxu[j]);
        float* row = op + (size_t)i * WOUT;               // 32B-aligned
        *reinterpret_cast<float4*>(row)     = make_float4(d[0], d[1], d[2], d[3]);
        *reinterpret_cast<float4*>(row + 4) = make_float4(d[4], d[5], d[6], d[7]);
    }
}

extern "C" void kernel_launch(void* const* d_in, const int* in_sizes, int n_in,
                              void* d_out, int out_size, void* d_ws, size_t ws_size,
                              hipStream_t stream) {
    const float* x  = (const float*)d_in[0];
    const float* w0 = (const float*)d_in[1];  const float* b0 = (const float*)d_in[2];
    const float* w1 = (const float*)d_in[3];  const float* b1 = (const float*)d_in[4];
    const float* w2 = (const float*)d_in[5];  const float* b2 = (const float*)d_in[6];
    const float* w3 = (const float*)d_in[7];  const float* b3 = (const float*)d_in[8];
    const float* w4 = (const float*)d_in[9];  const float* b4 = (const float*)d_in[10];
    const float* wc = (const float*)d_in[11]; const float* bc = (const float*)d_in[12];
    float* out = (float*)d_out;

    char* ws = (char*)d_ws;
    ushort_t* f0  = (ushort_t*)(ws + WS_F0);
    float*    wt1 = (float*)(ws + WS_WT1);
    float*    wt2 = (float*)(ws + WS_WT2);
    ushort_t* h1  = (ushort_t*)(ws + WS_H1);   // 12.97 MB

    hipLaunchKernelGGL(prep_w, dim3((NPREP + 255) / 256), dim3(256), 0, stream,
                       w0, w1, w2, f0, wt1, wt2);
    hipLaunchKernelGGL(k1_conv0, dim3(NPOS / 64), dim3(256), 0, stream,
                       x, f0, b0, h1);
    hipLaunchKernelGGL(k2_rest, dim3(NPOS / 256), dim3(256), 0, stream,
                       h1, wt1, b1, wt2, b2, w3, b3, w4, b4, wc, bc, out);
}

// Round 9
// 122.930 us; speedup vs baseline: 1.2096x; 1.2096x over previous
//
#include <hip/hip_runtime.h>
#include <hip/hip_bf16.h>

// Problem geometry
#define NB   16
#define C0   128
#define HH   44
#define WW   144
#define HW   (HH * WW)        // 6336
#define NPOS (NB * HW)        // 101376
#define SC   8
#define WOUT (WW * SC)        // 1152
#define HOUT (HH * SC)        // 352
#define PI_F 3.1415926535f

typedef __attribute__((ext_vector_type(8)))  short bf8;   // 8 bf16 (A/B frag, 4 VGPR)
typedef __attribute__((ext_vector_type(4)))  float f4;
typedef __attribute__((ext_vector_type(16))) float f16v;  // 32x32 C/D frag (16 AGPR)
typedef unsigned short ushort_t;

// frag-exact bf16 weight layout in ws (ushort elements), 32x32x16 B-frags:
//   conv0: 16 chunks (t*8+s) x [64 lanes][8]   -> 8192
//   conv1:  4 chunks (s)     x [64 lanes][8]   -> 2048
//   conv2:  2 chunks (s)     x [64 lanes][8]   -> 1024  (N padded 16->32, zeros)
#define F0 0
#define F1 8192
#define F2 10240
#define NWT 11264

__device__ __forceinline__ unsigned f2bf(float f) {
    union { float f; unsigned u; } v; v.f = f;
    unsigned r = v.u + 0x7FFFu + ((v.u >> 16) & 1u);     // RNE
    return r >> 16;
}
__device__ __forceinline__ float eluf(float x) {
    return x > 0.f ? x : (__expf(x) - 1.f);
}
__device__ __forceinline__ float sigmoidf(float x) {
    return 1.f / (1.f + __expf(-x));
}
// C/D row map for 32x32 MFMA: reg r, k-group g -> position row
__device__ __forceinline__ int crow(int r, int g) {
    return (r & 3) + 8 * (r >> 2) + 4 * g;
}

// ---- prep: pack w0/w1/w2 into 32x32x16 B-fragment order (bf16) ----
// B[k][n] frag: lane -> n = lane&31, k = (lane>>5)*8 + j (+16*s +...).
__global__ void prep_w(const float* __restrict__ w0, const float* __restrict__ w1,
                       const float* __restrict__ w2, ushort_t* __restrict__ ws) {
    int i = blockIdx.x * 256 + (int)threadIdx.x;
    int j = i & 7, lane = (i >> 3) & 63;
    int n = lane & 31, g = lane >> 5;
    if (i < 8192) {
        int c = i >> 9;                       // c = t*8 + s
        int s = c & 7, t = c >> 3;
        ws[F0 + i] = (ushort_t)f2bf(w0[(t * 32 + n) * 128 + s * 16 + g * 8 + j]);
    } else if (i < 10240) {
        int i2 = i - 8192;
        int s = i2 >> 9;                      // 0..3
        ws[F1 + i2] = (ushort_t)f2bf(w1[n * 64 + s * 16 + g * 8 + j]);
    } else if (i < NWT) {
        int i2 = i - 10240;
        int s = i2 >> 9;                      // 0..1
        ws[F2 + i2] = (n < 16) ? (ushort_t)f2bf(w2[n * 32 + s * 16 + g * 8 + j])
                               : (ushort_t)0;
    }
}

// One wave = 32 consecutive positions via 32x32x16 bf16 MFMA.
// x loads: per instr 2 channels x 32 consecutive pos = 2 FULL 128B lines.
// conv0 (16 MFMA) -> LDS RT -> conv1 (4) -> LDS RT -> conv2 (2, N-padded)
// -> VALU tail redundant x2 (lane g handles output rows 4g..4g+3).
// B-frags from pre-packed global ws (L2-resident). No barriers.
__global__ __launch_bounds__(256, 3)
void lpg32(const float* __restrict__ x, const ushort_t* __restrict__ wsb,
           const float* __restrict__ b0, const float* __restrict__ b1,
           const float* __restrict__ b2, const float* __restrict__ b3,
           const float* __restrict__ w3, const float* __restrict__ w4,
           const float* __restrict__ b4,
           const float* __restrict__ wc, const float* __restrict__ bc,
           float* __restrict__ out) {
    __shared__ __align__(16) ushort_t hb1s[4][2304];   // [pos32][64+8] bf16
    __shared__ __align__(16) ushort_t hb2s[4][1280];   // [pos32][32+8] bf16
    __shared__ __align__(16) float    hb3s[4][640];    // [pos32][16+4] fp32

    const int tid  = (int)threadIdx.x;
    const int lane = tid & 63;
    const int wid  = tid >> 6;
    const int m    = lane & 31;          // position-in-tile / C-col channel
    const int g    = lane >> 5;          // k-group 0/1

    const int pm  = blockIdx.x * 128 + wid * 32 + m;   // this lane's position
    const int bm  = pm / HW;
    const int hwm = pm - bm * HW;
    const float* xb = x + (size_t)bm * (C0 * HW) + hwm;

    // ---- conv0: 128 -> 64, A loaded per K-step (8 ch), 2 N-tiles x 8 K ----
    bf8 A[8];
#pragma unroll
    for (int s = 0; s < 8; ++s) {
        float xr[8];
#pragma unroll
        for (int j = 0; j < 8; ++j)
            xr[j] = xb[(s * 16 + g * 8 + j) * HW];     // 2 full lines / instr
        bf8 a;
#pragma unroll
        for (int j = 0; j < 8; j += 2) {
            __hip_bfloat162 pck = __float22bfloat162_rn(make_float2(xr[j], xr[j + 1]));
            union { __hip_bfloat162 b; short s2[2]; } u; u.b = pck;
            a[j] = u.s2[0]; a[j + 1] = u.s2[1];
        }
        A[s] = a;
    }

    f16v acc0, acc1;
    {
        const float bb0 = b0[m], bb1 = b0[32 + m];
#pragma unroll
        for (int r = 0; r < 16; ++r) { acc0[r] = bb0; acc1[r] = bb1; }
    }
#pragma unroll
    for (int s = 0; s < 8; ++s) {
        bf8 B = *(const bf8*)(wsb + F0 + (0 * 8 + s) * 512 + lane * 8);
        acc0 = __builtin_amdgcn_mfma_f32_32x32x16_bf16(A[s], B, acc0, 0, 0, 0);
    }
#pragma unroll
    for (int s = 0; s < 8; ++s) {
        bf8 B = *(const bf8*)(wsb + F0 + (1 * 8 + s) * 512 + lane * 8);
        acc1 = __builtin_amdgcn_mfma_f32_32x32x16_bf16(A[s], B, acc1, 0, 0, 0);
    }

    // ELU + scatter C-layout -> h1[pos][ch] bf16 (ch = t*32 + m, row = crow)
    ushort_t* h1p = &hb1s[wid][0];
#pragma unroll
    for (int r = 0; r < 16; ++r) {
        const int row = crow(r, g);
        h1p[row * 72 + m]      = (ushort_t)f2bf(eluf(acc0[r]));
        h1p[row * 72 + 32 + m] = (ushort_t)f2bf(eluf(acc1[r]));
    }

    // ---- conv1: 64 -> 32, 4 K-steps ----
    bf8 A1[4];
#pragma unroll
    for (int s = 0; s < 4; ++s)
        A1[s] = *(const bf8*)(h1p + m * 72 + s * 16 + g * 8);
    f16v c1;
    {
        const float bb = b1[m];
#pragma unroll
        for (int r = 0; r < 16; ++r) c1[r] = bb;
    }
#pragma unroll
    for (int s = 0; s < 4; ++s) {
        bf8 B = *(const bf8*)(wsb + F1 + s * 512 + lane * 8);
        c1 = __builtin_amdgcn_mfma_f32_32x32x16_bf16(A1[s], B, c1, 0, 0, 0);
    }
    ushort_t* h2p = &hb2s[wid][0];
#pragma unroll
    for (int r = 0; r < 16; ++r)
        h2p[crow(r, g) * 40 + m] = (ushort_t)f2bf(eluf(c1[r]));

    // ---- conv2: 32 -> 16 (N padded to 32; cols 16..31 are zero-weight) ----
    bf8 A2[2];
#pragma unroll
    for (int s = 0; s < 2; ++s)
        A2[s] = *(const bf8*)(h2p + m * 40 + s * 16 + g * 8);
    f16v c2;
    {
        const float bb = (m < 16) ? b2[m & 15] : 0.f;
#pragma unroll
        for (int r = 0; r < 16; ++r) c2[r] = bb;
    }
#pragma unroll
    for (int s = 0; s < 2; ++s) {
        bf8 B = *(const bf8*)(wsb + F2 + s * 512 + lane * 8);
        c2 = __builtin_amdgcn_mfma_f32_32x32x16_bf16(A2[s], B, c2, 0, 0, 0);
    }
    float* h3p = &hb3s[wid][0];
    if (m < 16) {
#pragma unroll
        for (int r = 0; r < 16; ++r)
            h3p[crow(r, g) * 20 + m] = eluf(c2[r]);
    }

    // ---- tail: lane handles pos m (2x redundant across g) ----
    float h3[16];
#pragma unroll
    for (int i = 0; i < 4; ++i) {
        f4 v = *(const f4*)(h3p + m * 20 + i * 4);
        h3[4 * i + 0] = v[0]; h3[4 * i + 1] = v[1];
        h3[4 * i + 2] = v[2]; h3[4 * i + 3] = v[3];
    }

    float h4v[8];
#pragma unroll
    for (int o = 0; o < 8; ++o) {
        float a = b3[o];                              // uniform -> s_load
#pragma unroll
        for (int c = 0; c < 16; ++c) a = fmaf(h3[c], w3[o * 16 + c], a);
        h4v[o] = eluf(a);
    }
    float h5v[4];
#pragma unroll
    for (int o = 0; o < 4; ++o) {
        float a = b4[o];
#pragma unroll
        for (int c = 0; c < 8; ++c) a = fmaf(h4v[c], w4[o * 8 + c], a);
        h5v[o] = a;                                   // no activation
    }
    float y0 = bc[0], y1 = bc[1], y2 = bc[2];
#pragma unroll
    for (int c = 0; c < 4; ++c) {
        y0 = fmaf(h5v[c], wc[0 * 4 + c], y0);
        y1 = fmaf(h5v[c], wc[1 * 4 + c], y1);
        y2 = fmaf(h5v[c], wc[2 * 4 + c], y2);
    }

    const float theta = sigmoidf(y0) * (PI_F / 6.0f);
    const float phi   = sigmoidf(y1) * (PI_F * 2.0f);
    const float dist  = sigmoidf(y2) * 81.0f;
    const float st = __sinf(theta), ct = __cosf(theta);
    const float sp = __sinf(phi),   cp = __cosf(phi);
    float nx = st * cp, ny = st * sp, nz = ct;
    const float inv = rsqrtf(fmaxf(nx * nx + ny * ny + nz * nz, 1e-24f));
    nx *= inv; ny *= inv; nz *= inv;

    // ---- 8x8 upsample: lane g writes rows 4g..4g+3 of its position ----
    const int hh = hwm / WW;
    const int wp = hwm - hh * WW;
    float* op = out + ((size_t)bm * HOUT + (size_t)hh * SC) * WOUT + (size_t)wp * SC;

    float nxu[8];
#pragma unroll
    for (int j = 0; j < 8; ++j) nxu[j] = nx * ((j - 3.5f) * 0.125f);

#pragma unroll
    for (int ii = 0; ii < 4; ++ii) {
        const int i = g * 4 + ii;
        const float den0 = fmaf(ny, (i - 3.5f) * 0.125f, nz);
        float d[8];
#pragma unroll
        for (int j = 0; j < 8; ++j)
            d[j] = dist * __builtin_amdgcn_rcpf(den0 + nxu[j]);
        float* row = op + (size_t)i * WOUT;           // 32B-aligned
        f4 v0 = (f4){d[0], d[1], d[2], d[3]};
        f4 v1 = (f4){d[4], d[5], d[6], d[7]};
        __builtin_nontemporal_store(v0, reinterpret_cast<f4*>(row));
        __builtin_nontemporal_store(v1, reinterpret_cast<f4*>(row + 4));
    }
}

extern "C" void kernel_launch(void* const* d_in, const int* in_sizes, int n_in,
                              void* d_out, int out_size, void* d_ws, size_t ws_size,
                              hipStream_t stream) {
    const float* x  = (const float*)d_in[0];
    const float* w0 = (const float*)d_in[1];  const float* b0 = (const float*)d_in[2];
    const float* w1 = (const float*)d_in[3];  const float* b1 = (const float*)d_in[4];
    const float* w2 = (const float*)d_in[5];  const float* b2 = (const float*)d_in[6];
    const float* w3 = (const float*)d_in[7];  const float* b3 = (const float*)d_in[8];
    const float* w4 = (const float*)d_in[9];  const float* b4 = (const float*)d_in[10];
    const float* wc = (const float*)d_in[11]; const float* bc = (const float*)d_in[12];
    ushort_t* ws = (ushort_t*)d_ws;            // 22,528 B used
    float* out = (float*)d_out;

    hipLaunchKernelGGL(prep_w, dim3((NWT + 255) / 256), dim3(256), 0, stream,
                       w0, w1, w2, ws);
    hipLaunchKernelGGL(lpg32, dim3(NPOS / 128), dim3(256), 0, stream,
                       x, ws, b0, b1, b2, b3, w3, w4, b4, wc, bc, out);
}